// Round 7
// baseline (627.889 us; speedup 1.0000x reference)
//
#include <hip/hip_runtime.h>
#include <math.h>

#define BN_EPS 1e-5f
#define HW_ 128

typedef unsigned short u16_t;
typedef unsigned int u32_t;

typedef __bf16 bf16x8 __attribute__((ext_vector_type(8)));
typedef __bf16 bf16v2 __attribute__((ext_vector_type(2)));
typedef float f32x4 __attribute__((ext_vector_type(4)));
typedef float f32x16 __attribute__((ext_vector_type(16)));
typedef u32_t u32x4 __attribute__((ext_vector_type(4)));
typedef u32_t u32x2 __attribute__((ext_vector_type(2)));
typedef u32x4 u32x4_ma __attribute__((may_alias));
typedef u32x2 u32x2_ma __attribute__((may_alias));
typedef f32x4 f32x4_ma __attribute__((may_alias));

// RNE f32->bf16 via compiler casts (emits v_cvt_pk_bf16_f32).
static __device__ __forceinline__ u16_t f2bf(float f) {
    union { __bf16 v; u16_t u; } x;
    x.v = (__bf16)f;
    return x.u;
}
static __device__ __forceinline__ u32_t packbf(float a, float b) {
    union { bf16v2 v; u32_t u; } x;
    bf16v2 p;
    p[0] = (__bf16)a;
    p[1] = (__bf16)b;
    x.v = p;
    return x.u;
}
static __device__ __forceinline__ bf16x8 ld_frag16(const u16_t* p) {
    union { u32x4 u; bf16x8 f; } x;
    x.u = *(const u32x4_ma*)p;
    return x.f;
}
static __device__ __forceinline__ bf16x8 ld_frag32(const u32_t* p) {
    union { u32x4 u; bf16x8 f; } x;
    x.u = *(const u32x4_ma*)p;
    return x.f;
}
static __device__ __forceinline__ bf16x8 asbf(u32x4 u) {
    union { u32x4 u; bf16x8 f; } x;
    x.u = u;
    return x.f;
}

// ---- d_ws table layout (u32 units) ----
#define WSUM_OFF 0        // 512 floats (per-image sigmoid sums)
#define W2R_OFF  512      // 9216 u32: [H][tap][32 ocl][16 icp] packed bf16 pairs
#define WF_OFF   9728     // 3*64 uint4 = 768 u32: conv1 B-frags [s][lane]
#define PT_OFF   10496    // 2560 u32: conv1 A base offsets (u32 units) [tt(40)][lane]
#define BN1_OFF  13056    // 64 u32: 32 x {inv, shift}
#define BN2_OFF  13120    // 128 u32: 64 x {inv, shift}
#define DONE_OFF 13248    // 1 u32: block-completion counter (last-block finalize)
#define WS_TOTAL 13249    // 52996 B

// crops tile: 36 rows x 37 cols x 4 ch (ch3 = 0), bf16. Pixel = 8 B (2 u32).
// Row pitch = 37*2 = 74 u32. Col 36 is an in-bounds pad (only ever hits kx=3,
// whose weight is 0 -> value irrelevant but must be finite).
#define CI_U32   (36 * 74)                // 2664 u32 = 10656 B
// hS pitch = 40 u16 (80 B): bank base of the phase-2 b128 read becomes
// 20p + 4swz (mod 32) -> near-uniform across all 32 banks (pitch 32 kept all
// 64 lanes of a tap on one 16-bank parity half = 2x the b128 floor).
#define HS_PITCH 40
// LDS: 10656 (uniS) + 23120 (hS) + 32 (red) = 33808 B -> 4 blocks/CU (wave-capped)

// ===== prep: build all block-invariant tables (16 blocks, grid-strided) =====
__global__ __launch_bounds__(512) void prep_kernel(
    const float* __restrict__ w1, const float* __restrict__ b1,
    const float* __restrict__ g1, const float* __restrict__ be1,
    const float* __restrict__ m1, const float* __restrict__ v1,
    const float* __restrict__ w2, const float* __restrict__ b2,
    const float* __restrict__ g2, const float* __restrict__ be2,
    const float* __restrict__ m2, const float* __restrict__ v2,
    u32_t* __restrict__ ws)
{
    const int gtid = blockIdx.x * 512 + threadIdx.x;   // 0..8191

    if (gtid < 512) ws[WSUM_OFF + gtid] = 0u;          // zero wsum[512]
    if (gtid == 512) ws[DONE_OFF] = 0u;                // zero completion counter

    // w2r: [H][tap][ocl][icp] = packbf(w2[oc][2icp][tap], w2[oc][2icp+1][tap])
    for (int idx = gtid; idx < 9216; idx += 8192) {
        int H   = idx / 4608;
        int rem = idx - H * 4608;
        int tap = rem >> 9;
        int r2  = rem & 511;
        int ocl = r2 >> 4;
        int icp = r2 & 15;
        const float* wp = w2 + (H * 32 + ocl) * 288 + tap;
        ws[W2R_OFF + idx] = packbf(wp[(2 * icp) * 9], wp[(2 * icp + 1) * 9]);
    }
    // wf: conv1 B-frag for (s=ky, lane): k = halfk*8+j; pixel kx = 2*halfk+(j>>2),
    // ch = j&3; value = w1[oc=n32][ch][ky][kx] for kx<3 && ch<3, else 0.
    if (gtid < 192) {
        int s = gtid >> 6, lane = gtid & 63;
        int n32 = lane & 31, h = lane >> 5;
        u32x4 f;
        #pragma unroll
        for (int jp = 0; jp < 4; ++jp) {
            int j0 = 2 * jp, j1 = 2 * jp + 1;
            int kx0 = 2 * h + (j0 >> 2), ch0 = j0 & 3;
            int kx1 = 2 * h + (j1 >> 2), ch1 = j1 & 3;
            float va = (kx0 < 3 && ch0 < 3) ? w1[n32 * 27 + ch0 * 9 + s * 3 + kx0] : 0.f;
            float vb = (kx1 < 3 && ch1 < 3) ? w1[n32 * 27 + ch1 * 9 + s * 3 + kx1] : 0.f;
            f[jp] = packbf(va, vb);
        }
        ((u32x4_ma*)(ws + WF_OFF))[gtid] = f;
    }
    // ptab: conv1 A base offset in u32 units for (tt<40, lane); pA clamped.
    if (gtid < 2560) {
        int tt = gtid >> 6, lane = gtid & 63;
        int n32 = lane & 31, h = lane >> 5;
        int gA = n32 >> 2, sub = n32 & 3;
        int pA = tt * 8 + gA;
        int gy = (pA * 241) >> 12; gy = min(gy, 16);
        int gx = min(pA - gy * 17, 16); gx = max(gx, 0);
        int cy = 2 * gy + (sub >> 1), cx = 2 * gx + (sub & 1);
        ws[PT_OFF + gtid] = (u32_t)((cy * 37 + cx + 2 * h) * 2);
    }
    if (gtid >= 1024 && gtid < 1056) {
        int ch = gtid - 1024;
        float inv = g1[ch] * rsqrtf(v1[ch] + BN_EPS);
        float sh  = b1[ch] * inv + be1[ch] - m1[ch] * inv;
        ws[BN1_OFF + 2 * ch]     = __float_as_uint(inv);
        ws[BN1_OFF + 2 * ch + 1] = __float_as_uint(sh);
    }
    if (gtid >= 2048 && gtid < 2112) {
        int ch = gtid - 2048;
        float inv = g2[ch] * rsqrtf(v2[ch] + BN_EPS);
        float sh  = b2[ch] * inv + be2[ch] - m2[ch] * inv;
        ws[BN2_OFF + 2 * ch]     = __float_as_uint(inv);
        ws[BN2_OFF + 2 * ch + 1] = __float_as_uint(sh);
    }
}

// ============================ fused CNN =====================================
// hS chunk swizzle: logical (group p, ch-chunk c of 4) stored at physical
// chunk c ^ ((p>>1)&3); combined with the 40-u16 pitch the phase-2 b128 read
// spreads ~uniformly over all 32 banks (the wave-read floor).
// blockIdx swizzle: HW assigns XCD = blockIdx%8 round-robin. Remap so each
// XCD runs a contiguous range of logical blocks => each image's 16 tiles
// (and its halo overlaps) stay in ONE XCD's L2.
__global__ __launch_bounds__(512, 8) void fused_cnn_kernel(
    const float* __restrict__ crops, const u32_t* __restrict__ tab,
    float* __restrict__ out, float* __restrict__ wsum)
{
    __shared__ __align__(16) u32_t uniS[CI_U32];        // crops 4-ch tile
    __shared__ __align__(16) u16_t hS[289 * HS_PITCH];  // pooled h (swizzled)
    __shared__ float redS[8];

    const int tid  = threadIdx.x;
    const int wave = tid >> 6;
    const int lane = tid & 63;
    const int quad = lane >> 4;
    const int r    = lane & 15;
    const int n32  = lane & 31;
    const int halfk = lane >> 5;

    // XCD-contiguous remap (bijective: 8192 = 8 * 1024)
    const int blk = ((blockIdx.x & 7) << 10) | (blockIdx.x >> 3);
    const int img = blk >> 4;
    const int t   = blk & 15;
    const int fy0 = (t >> 2) * 4;
    const int fx0 = (t & 3) * 4;
    const int crop_y0 = 8 * fy0 - 3;
    const int crop_x0 = 8 * fx0 - 3;
    const bool interior = (fy0 != 0) && (fx0 != 0);

    // ---- Phase 0: stage crops tile, pixel-quad tasks ----
    const float* cbase = crops + (size_t)img * (3 * HW_ * HW_);
    const int x0a = crop_x0 - 1;
    if (tid < 360) {
        int row = (tid * 6554) >> 16;              // tid/10 (exact)
        int vec = tid - row * 10;
        int gr  = crop_y0 + row;
        int col0 = x0a + 4 * vec;                  // 16-B aligned
        f32x4 c0 = {0.f,0.f,0.f,0.f}, c1 = {0.f,0.f,0.f,0.f}, c2 = {0.f,0.f,0.f,0.f};
        if ((unsigned)gr < 128u) {
            const float* rp = cbase + gr * HW_;
            if (col0 >= 0 && col0 <= 124) {        // fast path: 3 vec4 loads
                c0 = *(const f32x4_ma*)(rp + col0);
                c1 = *(const f32x4_ma*)(rp + HW_ * HW_ + col0);
                c2 = *(const f32x4_ma*)(rp + 2 * HW_ * HW_ + col0);
            } else {                               // edge: predicated scalars
                #pragma unroll
                for (int j = 0; j < 4; ++j) {
                    int gc = col0 + j;
                    if ((unsigned)gc < 128u) {
                        c0[j] = rp[gc];
                        c1[j] = rp[HW_ * HW_ + gc];
                        c2[j] = rp[2 * HW_ * HW_ + gc];
                    }
                }
            }
        }
        const int ccb = 4 * vec - 1;               // tile col of elem 0
        u32_t* up = uniS + (row * 37 + ccb) * 2;
        #pragma unroll
        for (int j = 0; j < 4; ++j) {
            if ((unsigned)(ccb + j) < 37u) {
                u32x2 w;
                w[0] = packbf(c0[j], c1[j]);
                w[1] = packbf(c2[j], 0.f);
                *(u32x2_ma*)(up + 2 * j) = w;
            }
        }
    }

    // ---- conv1 B-frags + bn1 + ptab offsets from tables (pre-barrier) ----
    u32x4 wf[3];
    const u32x4_ma* wft = (const u32x4_ma*)(tab + WF_OFF);
    #pragma unroll
    for (int s = 0; s < 3; ++s) wf[s] = wft[s * 64 + lane];
    u32_t pofs[5];
    #pragma unroll
    for (int i = 0; i < 5; ++i) pofs[i] = tab[PT_OFF + (wave + 8 * i) * 64 + lane];
    const float inv1 = __uint_as_float(tab[BN1_OFF + 2 * n32]);
    const float sh1  = __uint_as_float(tab[BN1_OFF + 2 * n32 + 1]);
    __syncthreads();

    // ---- Phase 1: conv1 via 32x32x16 MFMA (3 K-steps), pool in-reg -> hS ----
    const int hsub = n32 & 7;                      // within-chunk ch offset
    const int hchk = n32 >> 3;                     // logical ch-chunk
    const int pbase = wave * 8 + halfk;            // pD = pbase + i*64 + 2q

    // per-q hS store bases (u16 units); trip i adds immediate i*64*HS_PITCH
    int hqi[4];
    #pragma unroll
    for (int q = 0; q < 4; ++q)
        hqi[q] = (wave * 8 + halfk + 2 * q) * HS_PITCH + ((hchk ^ q) << 3) + hsub;

    const f32x16 z16 = {0.f,0.f,0.f,0.f,0.f,0.f,0.f,0.f,
                        0.f,0.f,0.f,0.f,0.f,0.f,0.f,0.f};

    auto conv_trip = [&](int ii) -> f32x16 {
        const u32_t* bp = uniS + pofs[ii];
        u32x2 l0a = *(const u32x2_ma*)(bp);
        u32x2 l0b = *(const u32x2_ma*)(bp + 2);
        u32x2 l1a = *(const u32x2_ma*)(bp + 74);
        u32x2 l1b = *(const u32x2_ma*)(bp + 76);
        u32x2 l2a = *(const u32x2_ma*)(bp + 148);
        u32x2 l2b = *(const u32x2_ma*)(bp + 150);
        u32x4 a0; a0[0] = l0a[0]; a0[1] = l0a[1]; a0[2] = l0b[0]; a0[3] = l0b[1];
        u32x4 a1; a1[0] = l1a[0]; a1[1] = l1a[1]; a1[2] = l1b[0]; a1[3] = l1b[1];
        u32x4 a2; a2[0] = l2a[0]; a2[1] = l2a[1]; a2[2] = l2b[0]; a2[3] = l2b[1];
        __builtin_amdgcn_s_setprio(1);
        f32x16 acc = __builtin_amdgcn_mfma_f32_32x32x16_bf16(asbf(a0), asbf(wf[0]), z16, 0, 0, 0);
        acc = __builtin_amdgcn_mfma_f32_32x32x16_bf16(asbf(a1), asbf(wf[1]), acc, 0, 0, 0);
        acc = __builtin_amdgcn_mfma_f32_32x32x16_bf16(asbf(a2), asbf(wf[2]), acc, 0, 0, 0);
        __builtin_amdgcn_s_setprio(0);
        return acc;
    };

    auto pool_val = [&](int ii, int q, const f32x16& acc) -> float {
        float m4 = fmaxf(fmaxf(fmaxf(acc[4 * q], acc[4 * q + 1]), acc[4 * q + 2]),
                         acc[4 * q + 3]);           // left-nested -> v_max3+v_max
        float val = fmaxf(fmaf(m4, inv1, sh1), 0.f);
        if (!interior) {              // edge tiles: zero outside global 64x64
            int pD  = pbase + ii * 64 + 2 * q;
            int gyD = (pD * 241) >> 12;
            int gxD = pD - gyD * 17;
            int y2 = 4 * fy0 - 1 + gyD, x2 = 4 * fx0 - 1 + gxD;
            if (y2 < 0 || y2 > 63 || x2 < 0 || x2 > 63) val = 0.f;
        }
        return val;
    };

    // trips 0..3: tt = wave+8i <= 31 -> all pD <= 255 < 289: plain stores
    #pragma unroll
    for (int i = 0; i < 4; ++i) {
        f32x16 acc = conv_trip(i);
        #pragma unroll
        for (int q = 0; q < 4; ++q)
            hS[hqi[q] + i * (64 * HS_PITCH)] = f2bf(pool_val(i, q, acc));
    }
    // trip 4: waves 0..3 full (tt=32..35, pD<=287); wave 4 only q=0,halfk=0
    // (tt=36 -> pD=288); waves 5..7 write nothing -> skip entirely.
    if (wave < 4) {
        f32x16 acc = conv_trip(4);
        #pragma unroll
        for (int q = 0; q < 4; ++q)
            hS[hqi[q] + 4 * (64 * HS_PITCH)] = f2bf(pool_val(4, q, acc));
    } else if (wave == 4) {
        f32x16 acc = conv_trip(4);
        float val = pool_val(4, 0, acc);
        if (halfk == 0) hS[hqi[0] + 4 * (64 * HS_PITCH)] = f2bf(val);
    }
    __syncthreads();   // hS complete

    // ---- Phase 2: conv2, both oc-halves in one pass (shared ah frags) ----
    float* outp = out + (size_t)img * 16384;
    const f32x4 zero4 = {0.f, 0.f, 0.f, 0.f};
    const int mt  = wave & 1;                      // oc-tile within half
    const int nt0 = wave >> 1;                     // feat row 0..3
    const int cy2 = 2 * nt0 + ((r >> 1) & 1);      // A-side conv-out row
    const int cx2 = 2 * (r >> 2) + (r & 1);        // A-side conv-out col
    const int fy  = fy0 + nt0;
    const int p0  = 34 * cy2 + 2 * cx2;            // tap(0,0) h-position

    const int oc0 = mt * 16 + r;
    const u32_t* wz0 = tab + W2R_OFF + oc0 * 16 + quad * 4;
    const u32_t* wz1 = wz0 + 4608;
    const float s2_0  = __uint_as_float(tab[BN2_OFF + 2 * oc0]);
    const float sh2_0 = __uint_as_float(tab[BN2_OFF + 2 * oc0 + 1]);
    const float s2_1  = __uint_as_float(tab[BN2_OFF + 64 + 2 * oc0]);
    const float sh2_1 = __uint_as_float(tab[BN2_OFF + 64 + 2 * oc0 + 1]);

    auto ld_ah = [&](int p) -> bf16x8 {
        return ld_frag16(&hS[p * HS_PITCH + (((quad ^ (p >> 1)) & 3) << 3)]);
    };

    f32x4 acc0 = zero4, acc1 = zero4;
    bf16x8 w0a = ld_frag32(wz0);
    bf16x8 w1a = ld_frag32(wz1);
    bf16x8 w0b = ld_frag32(wz0 + 512);
    bf16x8 w1b = ld_frag32(wz1 + 512);
    bf16x8 ahn = ld_ah(p0);
    __builtin_amdgcn_s_setprio(1);
    #pragma unroll
    for (int s = 0; s < 9; ++s) {
        bf16x8 ah = ahn;
        if (s < 8) {
            const int ns = s + 1;
            const int nky = ns / 3, nkx = ns - 3 * nky;
            ahn = ld_ah(p0 + nky * 17 + nkx);
        }
        bf16x8 cw0 = w0a, cw1 = w1a;
        w0a = w0b; w1a = w1b;
        if (s < 7) {
            w0b = ld_frag32(wz0 + (s + 2) * 512);
            w1b = ld_frag32(wz1 + (s + 2) * 512);
        }
        acc0 = __builtin_amdgcn_mfma_f32_16x16x32_bf16(ah, cw0, acc0, 0, 0, 0);
        acc1 = __builtin_amdgcn_mfma_f32_16x16x32_bf16(ah, cw1, acc1, 0, 0, 0);
    }
    __builtin_amdgcn_s_setprio(0);

    float m40 = fmaxf(fmaxf(fmaxf(acc0[0], acc0[1]), acc0[2]), acc0[3]);
    float z0  = fmaf(m40, s2_0, sh2_0);
    float sig0 = 1.f / (1.f + __expf(-z0));
    outp[oc0 * 256 + fy * 16 + fx0 + quad] = sig0;
    float m41 = fmaxf(fmaxf(fmaxf(acc1[0], acc1[1]), acc1[2]), acc1[3]);
    float z1  = fmaf(m41, s2_1, sh2_1);
    float sig1 = 1.f / (1.f + __expf(-z1));
    outp[(32 + oc0) * 256 + fy * 16 + fx0 + quad] = sig1;
    float ssum = sig0 + sig1;

    // ---- block score partial -> global atomic; last block finalizes ----
    #pragma unroll
    for (int off = 32; off > 0; off >>= 1)
        ssum += __shfl_xor(ssum, off);
    if (lane == 0) redS[wave] = ssum;
    __syncthreads();
    if (tid == 0) {
        float bs = 0.f;
        #pragma unroll
        for (int w = 0; w < 8; ++w) bs += redS[w];
        atomicAdd(&wsum[img], bs);
        __threadfence();                            // publish before counting
        u32_t old = atomicAdd((u32_t*)wsum + DONE_OFF, 1u);
        redS[0] = (old == 8191u) ? 1.f : 0.f;       // last-block flag
    }
    __syncthreads();
    if (redS[0] != 0.f) {                           // last block: finalize
        __threadfence();                            // acquire all wsum adds
        float s = atomicAdd(&wsum[tid], 0.0f);      // coherent read
        float mean = s * (1.f / 16384.f);
        out[8388608 + tid] = mean;                  // scores
        out[8388608 + 512 + tid] = (mean >= 0.55f) ? 1.f : 0.f;  // detected
    }
}

extern "C" void kernel_launch(void* const* d_in, const int* in_sizes, int n_in,
                              void* d_out, int out_size, void* d_ws, size_t ws_size,
                              hipStream_t stream) {
    (void)in_sizes; (void)n_in; (void)out_size; (void)ws_size;
    const float* crops = (const float*)d_in[0];
    const float* w1  = (const float*)d_in[1];
    const float* b1  = (const float*)d_in[2];
    const float* g1  = (const float*)d_in[3];
    const float* be1 = (const float*)d_in[4];
    const float* m1  = (const float*)d_in[5];
    const float* v1  = (const float*)d_in[6];
    const float* w2  = (const float*)d_in[7];
    const float* b2  = (const float*)d_in[8];
    const float* g2  = (const float*)d_in[9];
    const float* be2 = (const float*)d_in[10];
    const float* m2  = (const float*)d_in[11];
    const float* v2  = (const float*)d_in[12];
    float* out = (float*)d_out;
    u32_t* ws  = (u32_t*)d_ws;

    prep_kernel<<<16, 512, 0, stream>>>(
        w1, b1, g1, be1, m1, v1, w2, b2, g2, be2, m2, v2, ws);
    fused_cnn_kernel<<<8192, 512, 0, stream>>>(
        crops, ws, out, (float*)ws);
}

// Round 8
// 256.476 us; speedup vs baseline: 2.4481x; 2.4481x over previous
//
#include <hip/hip_runtime.h>
#include <math.h>

#define BN_EPS 1e-5f
#define HW_ 128

typedef unsigned short u16_t;
typedef unsigned int u32_t;

typedef __bf16 bf16x8 __attribute__((ext_vector_type(8)));
typedef __bf16 bf16v2 __attribute__((ext_vector_type(2)));
typedef float f32x4 __attribute__((ext_vector_type(4)));
typedef float f32x16 __attribute__((ext_vector_type(16)));
typedef u32_t u32x4 __attribute__((ext_vector_type(4)));
typedef u32_t u32x2 __attribute__((ext_vector_type(2)));
typedef u32x4 u32x4_ma __attribute__((may_alias));
typedef u32x2 u32x2_ma __attribute__((may_alias));
typedef f32x4 f32x4_ma __attribute__((may_alias));

// RNE f32->bf16 via compiler casts (emits v_cvt_pk_bf16_f32).
static __device__ __forceinline__ u16_t f2bf(float f) {
    union { __bf16 v; u16_t u; } x;
    x.v = (__bf16)f;
    return x.u;
}
static __device__ __forceinline__ u32_t packbf(float a, float b) {
    union { bf16v2 v; u32_t u; } x;
    bf16v2 p;
    p[0] = (__bf16)a;
    p[1] = (__bf16)b;
    x.v = p;
    return x.u;
}
static __device__ __forceinline__ bf16x8 ld_frag16(const u16_t* p) {
    union { u32x4 u; bf16x8 f; } x;
    x.u = *(const u32x4_ma*)p;
    return x.f;
}
static __device__ __forceinline__ bf16x8 ld_frag32(const u32_t* p) {
    union { u32x4 u; bf16x8 f; } x;
    x.u = *(const u32x4_ma*)p;
    return x.f;
}
static __device__ __forceinline__ bf16x8 asbf(u32x4 u) {
    union { u32x4 u; bf16x8 f; } x;
    x.u = u;
    return x.f;
}

// ---- d_ws table layout (u32 units) ----
#define WSUM_OFF 0        // 512 floats (per-image sigmoid sums)
#define W2R_OFF  512      // 9216 u32: [H][tap][32 ocl][16 icp] packed bf16 pairs
#define WF_OFF   9728     // 3*64 uint4 = 768 u32: conv1 B-frags [s][lane]
#define PT_OFF   10496    // 2560 u32: conv1 A base offsets (u32 units) [tt(40)][lane]
#define BN1_OFF  13056    // 64 u32: 32 x {inv, shift}
#define BN2_OFF  13120    // 128 u32: 64 x {inv, shift}
#define WS_TOTAL 13248    // 52992 B

// crops tile: 36 rows x 37 cols x 4 ch (ch3 = 0), bf16. Pixel = 8 B (2 u32).
// Row pitch = 37*2 = 74 u32. Col 36 is an in-bounds pad (only ever hits kx=3,
// whose weight is 0 -> value irrelevant but must be finite).
#define CI_U32   (36 * 74)                // 2664 u32 = 10656 B
// hS layout: rows paired into 128-B groups of 8 x 16-B slots. Logical
// (row p, chunk cl) lives at slot s = ((p&1 ^ (p>>1)&1)<<2) | (cl ^ ((p>>1)&3)).
// Phase-2 b128 reads: all 32 banks, 8 accesses/bank (floor).
// Phase-1 b16 stores: all 32 banks, 1 dword/bank (conflict-free).
// 145 pairs * 128 B = 18560 B.
// LDS: 10656 (uniS) + 18560 (hS) + 32 (red) = 29248 B -> 4 blocks/CU (wave-cap)

// ===== prep: build all block-invariant tables (16 blocks, grid-strided) =====
__global__ __launch_bounds__(512) void prep_kernel(
    const float* __restrict__ w1, const float* __restrict__ b1,
    const float* __restrict__ g1, const float* __restrict__ be1,
    const float* __restrict__ m1, const float* __restrict__ v1,
    const float* __restrict__ w2, const float* __restrict__ b2,
    const float* __restrict__ g2, const float* __restrict__ be2,
    const float* __restrict__ m2, const float* __restrict__ v2,
    u32_t* __restrict__ ws)
{
    const int gtid = blockIdx.x * 512 + threadIdx.x;   // 0..8191

    if (gtid < 512) ws[WSUM_OFF + gtid] = 0u;          // zero wsum[512]

    // w2r: [H][tap][ocl][icp] = packbf(w2[oc][2icp][tap], w2[oc][2icp+1][tap])
    for (int idx = gtid; idx < 9216; idx += 8192) {
        int H   = idx / 4608;
        int rem = idx - H * 4608;
        int tap = rem >> 9;
        int r2  = rem & 511;
        int ocl = r2 >> 4;
        int icp = r2 & 15;
        const float* wp = w2 + (H * 32 + ocl) * 288 + tap;
        ws[W2R_OFF + idx] = packbf(wp[(2 * icp) * 9], wp[(2 * icp + 1) * 9]);
    }
    // wf: conv1 B-frag for (s=ky, lane): k = halfk*8+j; pixel kx = 2*halfk+(j>>2),
    // ch = j&3; value = w1[oc=n32][ch][ky][kx] for kx<3 && ch<3, else 0.
    if (gtid < 192) {
        int s = gtid >> 6, lane = gtid & 63;
        int n32 = lane & 31, h = lane >> 5;
        u32x4 f;
        #pragma unroll
        for (int jp = 0; jp < 4; ++jp) {
            int j0 = 2 * jp, j1 = 2 * jp + 1;
            int kx0 = 2 * h + (j0 >> 2), ch0 = j0 & 3;
            int kx1 = 2 * h + (j1 >> 2), ch1 = j1 & 3;
            float va = (kx0 < 3 && ch0 < 3) ? w1[n32 * 27 + ch0 * 9 + s * 3 + kx0] : 0.f;
            float vb = (kx1 < 3 && ch1 < 3) ? w1[n32 * 27 + ch1 * 9 + s * 3 + kx1] : 0.f;
            f[jp] = packbf(va, vb);
        }
        ((u32x4_ma*)(ws + WF_OFF))[gtid] = f;
    }
    // ptab: conv1 A base offset in u32 units for (tt<40, lane); pA clamped.
    if (gtid < 2560) {
        int tt = gtid >> 6, lane = gtid & 63;
        int n32 = lane & 31, h = lane >> 5;
        int gA = n32 >> 2, sub = n32 & 3;
        int pA = tt * 8 + gA;
        int gy = (pA * 241) >> 12; gy = min(gy, 16);
        int gx = min(pA - gy * 17, 16); gx = max(gx, 0);
        int cy = 2 * gy + (sub >> 1), cx = 2 * gx + (sub & 1);
        ws[PT_OFF + gtid] = (u32_t)((cy * 37 + cx + 2 * h) * 2);
    }
    if (gtid >= 1024 && gtid < 1056) {
        int ch = gtid - 1024;
        float inv = g1[ch] * rsqrtf(v1[ch] + BN_EPS);
        float sh  = b1[ch] * inv + be1[ch] - m1[ch] * inv;
        ws[BN1_OFF + 2 * ch]     = __float_as_uint(inv);
        ws[BN1_OFF + 2 * ch + 1] = __float_as_uint(sh);
    }
    if (gtid >= 2048 && gtid < 2112) {
        int ch = gtid - 2048;
        float inv = g2[ch] * rsqrtf(v2[ch] + BN_EPS);
        float sh  = b2[ch] * inv + be2[ch] - m2[ch] * inv;
        ws[BN2_OFF + 2 * ch]     = __float_as_uint(inv);
        ws[BN2_OFF + 2 * ch + 1] = __float_as_uint(sh);
    }
}

// ============================ fused CNN =====================================
// blockIdx swizzle: HW assigns XCD = blockIdx%8 round-robin. Remap so each
// XCD runs a contiguous range of logical blocks => each image's 16 tiles
// (and its halo overlaps) stay in ONE XCD's L2.
__global__ __launch_bounds__(512, 8) void fused_cnn_kernel(
    const float* __restrict__ crops, const u32_t* __restrict__ tab,
    float* __restrict__ out, float* __restrict__ wsum)
{
    __shared__ __align__(16) u32_t uniS[CI_U32];   // crops 4-ch interleaved tile
    __shared__ __align__(16) u16_t hS[145 * 64];   // pooled h (pair-swizzled)
    __shared__ float redS[8];

    const int tid  = threadIdx.x;
    const int wave = tid >> 6;
    const int lane = tid & 63;
    const int quad = lane >> 4;
    const int r    = lane & 15;
    const int n32  = lane & 31;
    const int halfk = lane >> 5;

    // XCD-contiguous remap (bijective: 8192 = 8 * 1024)
    const int blk = ((blockIdx.x & 7) << 10) | (blockIdx.x >> 3);
    const int img = blk >> 4;
    const int t   = blk & 15;
    const int fy0 = (t >> 2) * 4;
    const int fx0 = (t & 3) * 4;
    const int crop_y0 = 8 * fy0 - 3;
    const int crop_x0 = 8 * fx0 - 3;
    const bool interior = (fy0 != 0) && (fx0 != 0);

    // ---- Phase 0: stage crops tile, pixel-quad tasks ----
    const float* cbase = crops + (size_t)img * (3 * HW_ * HW_);
    const int x0a = crop_x0 - 1;
    if (tid < 360) {
        int row = (tid * 6554) >> 16;              // tid/10 (exact, tid<1080)
        int vec = tid - row * 10;
        int gr  = crop_y0 + row;
        int col0 = x0a + 4 * vec;                  // 16-B aligned
        f32x4 c0 = {0.f,0.f,0.f,0.f}, c1 = {0.f,0.f,0.f,0.f}, c2 = {0.f,0.f,0.f,0.f};
        if ((unsigned)gr < 128u) {
            const float* rp = cbase + gr * HW_;
            if (col0 >= 0 && col0 <= 124) {        // fast path: 3 vec4 loads
                c0 = *(const f32x4_ma*)(rp + col0);
                c1 = *(const f32x4_ma*)(rp + HW_ * HW_ + col0);
                c2 = *(const f32x4_ma*)(rp + 2 * HW_ * HW_ + col0);
            } else {                               // edge: predicated scalars
                #pragma unroll
                for (int j = 0; j < 4; ++j) {
                    int gc = col0 + j;
                    if ((unsigned)gc < 128u) {
                        c0[j] = rp[gc];
                        c1[j] = rp[HW_ * HW_ + gc];
                        c2[j] = rp[2 * HW_ * HW_ + gc];
                    }
                }
            }
        }
        const int ccb = 4 * vec - 1;               // tile col of elem 0
        u32_t* up = uniS + (row * 37 + ccb) * 2;
        #pragma unroll
        for (int j = 0; j < 4; ++j) {
            if ((unsigned)(ccb + j) < 37u) {
                u32x2 w;
                w[0] = packbf(c0[j], c1[j]);
                w[1] = packbf(c2[j], 0.f);
                *(u32x2_ma*)(up + 2 * j) = w;
            }
        }
    }

    // ---- conv1 B-frags + bn1 + ptab offsets from tables (pre-barrier) ----
    u32x4 wf[3];
    const u32x4_ma* wft = (const u32x4_ma*)(tab + WF_OFF);
    #pragma unroll
    for (int s = 0; s < 3; ++s) wf[s] = wft[s * 64 + lane];
    u32_t pofs[5];
    #pragma unroll
    for (int i = 0; i < 5; ++i) pofs[i] = tab[PT_OFF + (wave + 8 * i) * 64 + lane];
    const float inv1 = __uint_as_float(tab[BN1_OFF + 2 * n32]);
    const float sh1  = __uint_as_float(tab[BN1_OFF + 2 * n32 + 1]);
    __syncthreads();

    // ---- Phase 1: conv1 via 32x32x16 MFMA (3 K-steps), pool in-reg -> hS ----
    const int hsub = n32 & 7;                      // within-chunk ch offset
    const int hchk = n32 >> 3;                     // logical ch-chunk
    const int pbase = wave * 8 + halfk;            // pD = pbase + i*64 + 2q

    // per-q hS store bases (u16 units); trip i adds immediate i*2048.
    // p = wave*8 + 64i + 2q + halfk -> p>>1 = wave*4 + 32i + q, p&1 = halfk,
    // v = (p>>1)&3 = q, e = q&1. slot s = ((halfk^e)<<2) | (hchk^q).
    int hqi[4];
    #pragma unroll
    for (int q = 0; q < 4; ++q) {
        int s = ((halfk ^ (q & 1)) << 2) | (hchk ^ q);
        hqi[q] = (wave * 4 + q) * 64 + s * 8 + hsub;
    }

    const f32x16 z16 = {0.f,0.f,0.f,0.f,0.f,0.f,0.f,0.f,
                        0.f,0.f,0.f,0.f,0.f,0.f,0.f,0.f};

    auto conv_trip = [&](int ii) -> f32x16 {
        const u32_t* bp = uniS + pofs[ii];
        u32x2 l0a = *(const u32x2_ma*)(bp);
        u32x2 l0b = *(const u32x2_ma*)(bp + 2);
        u32x2 l1a = *(const u32x2_ma*)(bp + 74);
        u32x2 l1b = *(const u32x2_ma*)(bp + 76);
        u32x2 l2a = *(const u32x2_ma*)(bp + 148);
        u32x2 l2b = *(const u32x2_ma*)(bp + 150);
        u32x4 a0; a0[0] = l0a[0]; a0[1] = l0a[1]; a0[2] = l0b[0]; a0[3] = l0b[1];
        u32x4 a1; a1[0] = l1a[0]; a1[1] = l1a[1]; a1[2] = l1b[0]; a1[3] = l1b[1];
        u32x4 a2; a2[0] = l2a[0]; a2[1] = l2a[1]; a2[2] = l2b[0]; a2[3] = l2b[1];
        f32x16 acc = __builtin_amdgcn_mfma_f32_32x32x16_bf16(asbf(a0), asbf(wf[0]), z16, 0, 0, 0);
        acc = __builtin_amdgcn_mfma_f32_32x32x16_bf16(asbf(a1), asbf(wf[1]), acc, 0, 0, 0);
        acc = __builtin_amdgcn_mfma_f32_32x32x16_bf16(asbf(a2), asbf(wf[2]), acc, 0, 0, 0);
        return acc;
    };

    auto pool_val = [&](int ii, int q, const f32x16& acc) -> float {
        float m4 = fmaxf(fmaxf(fmaxf(acc[4 * q], acc[4 * q + 1]), acc[4 * q + 2]),
                         acc[4 * q + 3]);
        float val = fmaxf(fmaf(m4, inv1, sh1), 0.f);
        if (!interior) {              // edge tiles: zero outside global 64x64
            int pD  = pbase + ii * 64 + 2 * q;
            int gyD = (pD * 241) >> 12;
            int gxD = pD - gyD * 17;
            int y2 = 4 * fy0 - 1 + gyD, x2 = 4 * fx0 - 1 + gxD;
            if (y2 < 0 || y2 > 63 || x2 < 0 || x2 > 63) val = 0.f;
        }
        return val;
    };

    // trips 0..3: tt = wave+8i <= 31 -> all pD <= 255 < 289: plain stores
    #pragma unroll
    for (int i = 0; i < 4; ++i) {
        f32x16 acc = conv_trip(i);
        #pragma unroll
        for (int q = 0; q < 4; ++q)
            hS[hqi[q] + i * 2048] = f2bf(pool_val(i, q, acc));
    }
    // trip 4: waves 0..3 full (tt=32..35, pD<=287); wave 4 only q=0,halfk=0
    // (tt=36 -> pD=288); waves 5..7 write nothing -> skip entirely.
    if (wave < 4) {
        f32x16 acc = conv_trip(4);
        #pragma unroll
        for (int q = 0; q < 4; ++q)
            hS[hqi[q] + 4 * 2048] = f2bf(pool_val(4, q, acc));
    } else if (wave == 4) {
        f32x16 acc = conv_trip(4);
        float val = pool_val(4, 0, acc);
        if (halfk == 0) hS[hqi[0] + 4 * 2048] = f2bf(val);
    }
    __syncthreads();   // hS complete

    // ---- Phase 2: conv2, both oc-halves in one pass (shared ah frags) ----
    // A = h positions (lane r), B = weights (global, L1/L2-hot). Software
    // pipeline: weight frags prefetched 2 taps ahead, ah 1 tap ahead.
    float* outp = out + (size_t)img * 16384;
    const f32x4 zero4 = {0.f, 0.f, 0.f, 0.f};
    const int mt  = wave & 1;                      // oc-tile within half
    const int nt0 = wave >> 1;                     // feat row 0..3
    const int cy2 = 2 * nt0 + ((r >> 1) & 1);      // A-side conv-out row
    const int cx2 = 2 * (r >> 2) + (r & 1);        // A-side conv-out col
    const int fy  = fy0 + nt0;
    const int p0  = 34 * cy2 + 2 * cx2;            // tap(0,0) h-position

    const int oc0 = mt * 16 + r;
    const u32_t* wz0 = tab + W2R_OFF + oc0 * 16 + quad * 4;
    const u32_t* wz1 = wz0 + 4608;
    // BN2 constants hoisted (hide L2 latency under the MFMA chain)
    const float s2_0  = __uint_as_float(tab[BN2_OFF + 2 * oc0]);
    const float sh2_0 = __uint_as_float(tab[BN2_OFF + 2 * oc0 + 1]);
    const float s2_1  = __uint_as_float(tab[BN2_OFF + 64 + 2 * oc0]);
    const float sh2_1 = __uint_as_float(tab[BN2_OFF + 64 + 2 * oc0 + 1]);

    // logical chunk quad of row p: pair ph = p>>1, slot
    // s = ((p&1 ^ ph&1)<<2) | (quad ^ (ph&3)); idx = ph*64 + s*8.
    auto ld_ah = [&](int p) -> bf16x8 {
        int ph = p >> 1;
        int s  = (((p ^ ph) & 1) << 2) | ((quad ^ ph) & 3);
        return ld_frag16(&hS[ph * 64 + s * 8]);
    };

    f32x4 acc0 = zero4, acc1 = zero4;
    bf16x8 w0a = ld_frag32(wz0);
    bf16x8 w1a = ld_frag32(wz1);
    bf16x8 w0b = ld_frag32(wz0 + 512);
    bf16x8 w1b = ld_frag32(wz1 + 512);
    bf16x8 ahn = ld_ah(p0);
    #pragma unroll
    for (int s = 0; s < 9; ++s) {
        bf16x8 ah = ahn;
        if (s < 8) {
            const int ns = s + 1;
            const int nky = ns / 3, nkx = ns - 3 * nky;
            ahn = ld_ah(p0 + nky * 17 + nkx);
        }
        bf16x8 cw0 = w0a, cw1 = w1a;
        w0a = w0b; w1a = w1b;
        if (s < 7) {
            w0b = ld_frag32(wz0 + (s + 2) * 512);
            w1b = ld_frag32(wz1 + (s + 2) * 512);
        }
        acc0 = __builtin_amdgcn_mfma_f32_16x16x32_bf16(ah, cw0, acc0, 0, 0, 0);
        acc1 = __builtin_amdgcn_mfma_f32_16x16x32_bf16(ah, cw1, acc1, 0, 0, 0);
    }

    float m40 = fmaxf(fmaxf(fmaxf(acc0[0], acc0[1]), acc0[2]), acc0[3]);
    float z0  = fmaf(m40, s2_0, sh2_0);
    float sig0 = 1.f / (1.f + __expf(-z0));
    outp[oc0 * 256 + fy * 16 + fx0 + quad] = sig0;
    float m41 = fmaxf(fmaxf(fmaxf(acc1[0], acc1[1]), acc1[2]), acc1[3]);
    float z1  = fmaf(m41, s2_1, sh2_1);
    float sig1 = 1.f / (1.f + __expf(-z1));
    outp[(32 + oc0) * 256 + fy * 16 + fx0 + quad] = sig1;
    float ssum = sig0 + sig1;

    // ---- block score partial -> global atomic ----
    #pragma unroll
    for (int off = 32; off > 0; off >>= 1)
        ssum += __shfl_xor(ssum, off);
    if (lane == 0) redS[wave] = ssum;
    __syncthreads();
    if (tid == 0) {
        float bs = 0.f;
        #pragma unroll
        for (int w = 0; w < 8; ++w) bs += redS[w];
        atomicAdd(&wsum[img], bs);
    }
}

__global__ void finalize_kernel(const float* __restrict__ ws,
                                float* __restrict__ scores,
                                float* __restrict__ detected) {
    int i = threadIdx.x;
    float mean = ws[i] * (1.f / 16384.f);
    scores[i] = mean;
    detected[i] = (mean >= 0.55f) ? 1.f : 0.f;
}

extern "C" void kernel_launch(void* const* d_in, const int* in_sizes, int n_in,
                              void* d_out, int out_size, void* d_ws, size_t ws_size,
                              hipStream_t stream) {
    (void)in_sizes; (void)n_in; (void)out_size; (void)ws_size;
    const float* crops = (const float*)d_in[0];
    const float* w1  = (const float*)d_in[1];
    const float* b1  = (const float*)d_in[2];
    const float* g1  = (const float*)d_in[3];
    const float* be1 = (const float*)d_in[4];
    const float* m1  = (const float*)d_in[5];
    const float* v1  = (const float*)d_in[6];
    const float* w2  = (const float*)d_in[7];
    const float* b2  = (const float*)d_in[8];
    const float* g2  = (const float*)d_in[9];
    const float* be2 = (const float*)d_in[10];
    const float* m2  = (const float*)d_in[11];
    const float* v2  = (const float*)d_in[12];
    float* out = (float*)d_out;
    u32_t* ws  = (u32_t*)d_ws;

    prep_kernel<<<16, 512, 0, stream>>>(
        w1, b1, g1, be1, m1, v1, w2, b2, g2, be2, m2, v2, ws);
    fused_cnn_kernel<<<8192, 512, 0, stream>>>(
        crops, ws, out, (float*)ws);
    finalize_kernel<<<1, 512, 0, stream>>>(
        (const float*)ws, out + 8388608, out + 8388608 + 512);
}

// Round 10
// 253.196 us; speedup vs baseline: 2.4799x; 1.0130x over previous
//
#include <hip/hip_runtime.h>
#include <math.h>

#define BN_EPS 1e-5f
#define HW_ 128

typedef unsigned short u16_t;
typedef unsigned int u32_t;

typedef __bf16 bf16x8 __attribute__((ext_vector_type(8)));
typedef __bf16 bf16v2 __attribute__((ext_vector_type(2)));
typedef float f32x4 __attribute__((ext_vector_type(4)));
typedef float f32x16 __attribute__((ext_vector_type(16)));
typedef u32_t u32x4 __attribute__((ext_vector_type(4)));
typedef u32_t u32x2 __attribute__((ext_vector_type(2)));
typedef u32x4 u32x4_ma __attribute__((may_alias));
typedef u32x2 u32x2_ma __attribute__((may_alias));
typedef f32x4 f32x4_ma __attribute__((may_alias));

// RNE f32->bf16 via compiler casts (emits v_cvt_pk_bf16_f32).
static __device__ __forceinline__ u16_t f2bf(float f) {
    union { __bf16 v; u16_t u; } x;
    x.v = (__bf16)f;
    return x.u;
}
static __device__ __forceinline__ u32_t packbf(float a, float b) {
    union { bf16v2 v; u32_t u; } x;
    bf16v2 p;
    p[0] = (__bf16)a;
    p[1] = (__bf16)b;
    x.v = p;
    return x.u;
}
static __device__ __forceinline__ bf16x8 ld_frag16(const u16_t* p) {
    union { u32x4 u; bf16x8 f; } x;
    x.u = *(const u32x4_ma*)p;
    return x.f;
}
static __device__ __forceinline__ bf16x8 ld_frag32(const u32_t* p) {
    union { u32x4 u; bf16x8 f; } x;
    x.u = *(const u32x4_ma*)p;
    return x.f;
}
static __device__ __forceinline__ bf16x8 asbf(u32x4 u) {
    union { u32x4 u; bf16x8 f; } x;
    x.u = u;
    return x.f;
}

// ---- d_ws table layout (u32 units) ----
#define WSUM_OFF 0        // 512 floats (per-image sigmoid sums)
#define W2R_OFF  512      // 9216 u32: [H][tap][32 ocl][16 icp] packed bf16 pairs
#define WF_OFF   9728     // 3*64 uint4 = 768 u32: conv1 B-frags [s][lane]
#define PT_OFF   10496    // 2560 u32: conv1 A base offsets (u32 units) [tt(40)][lane]
#define BN2_OFF  13120    // 128 u32: 64 x {inv, shift}
#define WS_TOTAL 13248    // 52992 B

// crops tile: 36 rows x 37 cols x 4 ch (ch3 = 1.0), bf16. Pixel = 8 B (2 u32).
// Row pitch = 37*2 = 74 u32. Col 36 is an in-bounds pad (only ever hits kx=3,
// whose weight is 0 -> value irrelevant but must be finite).
// BN1 is folded into the conv1 B-matrix: wf = w1*inv1 for ch<3; the shift sh1
// is carried by the constant ch3=1.0 plane via a hi/lo bf16 split at taps
// (ky=0,kx=0) and (ky=0,kx=1) -> MFMA adds sh1 at ~f32 precision for free.
#define CI_U32   (36 * 74)                // 2664 u32 = 10656 B
// LDS: 10656 (uniS) + 18496 (hS) + 32 (red) = 29184 B -> wave-capped 4 blocks/CU

// ===== prep: build all block-invariant tables (16 blocks, grid-strided) =====
__global__ __launch_bounds__(512) void prep_kernel(
    const float* __restrict__ w1, const float* __restrict__ b1,
    const float* __restrict__ g1, const float* __restrict__ be1,
    const float* __restrict__ m1, const float* __restrict__ v1,
    const float* __restrict__ w2, const float* __restrict__ b2,
    const float* __restrict__ g2, const float* __restrict__ be2,
    const float* __restrict__ m2, const float* __restrict__ v2,
    u32_t* __restrict__ ws)
{
    const int gtid = blockIdx.x * 512 + threadIdx.x;   // 0..8191

    if (gtid < 512) ws[WSUM_OFF + gtid] = 0u;          // zero wsum[512]

    // w2r: [H][tap][ocl][icp] = packbf(w2[oc][2icp][tap], w2[oc][2icp+1][tap])
    for (int idx = gtid; idx < 9216; idx += 8192) {
        int H   = idx / 4608;
        int rem = idx - H * 4608;
        int tap = rem >> 9;
        int r2  = rem & 511;
        int ocl = r2 >> 4;
        int icp = r2 & 15;
        const float* wp = w2 + (H * 32 + ocl) * 288 + tap;
        ws[W2R_OFF + idx] = packbf(wp[(2 * icp) * 9], wp[(2 * icp + 1) * 9]);
    }
    // wf: conv1 B-frag for (s=ky, lane): k = halfk*8+j; pixel kx = 2*halfk+(j>>2),
    // ch = j&3. ch<3 & kx<3: w1[oc][ch][ky][kx]*inv1[oc]. ch==3: sh_hi at
    // (ky=0,kx=0), sh_lo at (ky=0,kx=1), else 0 (incl. all of kx==3).
    if (gtid < 192) {
        int s = gtid >> 6, lane = gtid & 63;
        int n32 = lane & 31, h = lane >> 5;
        float inv = g1[n32] * rsqrtf(v1[n32] + BN_EPS);
        float sh  = b1[n32] * inv + be1[n32] - m1[n32] * inv;
        float sh_hi = (float)(__bf16)sh;            // bf16-rounded hi part
        float sh_lo = sh - sh_hi;                   // residual (fits bf16 rel)
        u32x4 f;
        #pragma unroll
        for (int jp = 0; jp < 4; ++jp) {
            int j0 = 2 * jp, j1 = 2 * jp + 1;
            int kx0 = 2 * h + (j0 >> 2), ch0 = j0 & 3;
            int kx1 = 2 * h + (j1 >> 2), ch1 = j1 & 3;
            float va = (kx0 < 3 && ch0 < 3) ? w1[n32 * 27 + ch0 * 9 + s * 3 + kx0] * inv : 0.f;
            float vb = (kx1 < 3 && ch1 < 3) ? w1[n32 * 27 + ch1 * 9 + s * 3 + kx1] * inv : 0.f;
            if (s == 0 && ch0 == 3) { if (kx0 == 0) va = sh_hi; else if (kx0 == 1) va = sh_lo; }
            if (s == 0 && ch1 == 3) { if (kx1 == 0) vb = sh_hi; else if (kx1 == 1) vb = sh_lo; }
            f[jp] = packbf(va, vb);
        }
        ((u32x4_ma*)(ws + WF_OFF))[gtid] = f;
    }
    // ptab: conv1 A base offset in u32 units for (tt<40, lane); pA clamped.
    if (gtid < 2560) {
        int tt = gtid >> 6, lane = gtid & 63;
        int n32 = lane & 31, h = lane >> 5;
        int gA = n32 >> 2, sub = n32 & 3;
        int pA = tt * 8 + gA;
        int gy = (pA * 241) >> 12; gy = min(gy, 16);
        int gx = min(pA - gy * 17, 16); gx = max(gx, 0);
        int cy = 2 * gy + (sub >> 1), cx = 2 * gx + (sub & 1);
        ws[PT_OFF + gtid] = (u32_t)((cy * 37 + cx + 2 * h) * 2);
    }
    if (gtid >= 2048 && gtid < 2112) {
        int ch = gtid - 2048;
        float inv = g2[ch] * rsqrtf(v2[ch] + BN_EPS);
        float sh  = b2[ch] * inv + be2[ch] - m2[ch] * inv;
        ws[BN2_OFF + 2 * ch]     = __float_as_uint(inv);
        ws[BN2_OFF + 2 * ch + 1] = __float_as_uint(sh);
    }
}

// ============================ fused CNN =====================================
// hS swizzle: logical (group p, ch-chunk c of 4) stored at physical chunk
// c ^ ((p>>1)&3) (verified: already at the b128 read floor; R7 probe showed
// hS contributes ~0 of SQ_LDS_BANK_CONFLICT).
// blockIdx swizzle: HW assigns XCD = blockIdx%8 round-robin. Remap so each
// XCD runs a contiguous range of logical blocks => each image's 16 tiles
// (and its halo overlaps) stay in ONE XCD's L2 (FETCH 134.7 -> 49.4 MB).
__global__ __launch_bounds__(512, 8) void fused_cnn_kernel(
    const float* __restrict__ crops, const u32_t* __restrict__ tab,
    float* __restrict__ out, float* __restrict__ wsum)
{
    __shared__ __align__(16) u32_t uniS[CI_U32];   // crops 4-ch interleaved tile
    __shared__ __align__(16) u16_t hS[289 * 32];   // pooled h (swizzled chunks)
    __shared__ float redS[8];

    const int tid  = threadIdx.x;
    const int wave = tid >> 6;
    const int lane = tid & 63;
    const int quad = lane >> 4;
    const int r    = lane & 15;
    const int n32  = lane & 31;
    const int halfk = lane >> 5;

    // XCD-contiguous remap (bijective: 8192 = 8 * 1024)
    const int blk = ((blockIdx.x & 7) << 10) | (blockIdx.x >> 3);
    const int img = blk >> 4;
    const int t   = blk & 15;
    const int fy0 = (t >> 2) * 4;
    const int fx0 = (t & 3) * 4;
    const int crop_y0 = 8 * fy0 - 3;
    const int crop_x0 = 8 * fx0 - 3;
    const bool interior = (fy0 != 0) && (fx0 != 0);

    // ---- Phase 0: stage crops tile, pixel-quad tasks (ch3 = 1.0 bias) ----
    const float* cbase = crops + (size_t)img * (3 * HW_ * HW_);
    const int x0a = crop_x0 - 1;
    if (tid < 360) {
        int row = (tid * 6554) >> 16;              // tid/10 (exact, tid<1080)
        int vec = tid - row * 10;
        int gr  = crop_y0 + row;
        int col0 = x0a + 4 * vec;                  // 16-B aligned
        f32x4 c0 = {0.f,0.f,0.f,0.f}, c1 = {0.f,0.f,0.f,0.f}, c2 = {0.f,0.f,0.f,0.f};
        if ((unsigned)gr < 128u) {
            const float* rp = cbase + gr * HW_;
            if (col0 >= 0 && col0 <= 124) {        // fast path: 3 vec4 loads
                c0 = *(const f32x4_ma*)(rp + col0);
                c1 = *(const f32x4_ma*)(rp + HW_ * HW_ + col0);
                c2 = *(const f32x4_ma*)(rp + 2 * HW_ * HW_ + col0);
            } else {                               // edge: predicated scalars
                #pragma unroll
                for (int j = 0; j < 4; ++j) {
                    int gc = col0 + j;
                    if ((unsigned)gc < 128u) {
                        c0[j] = rp[gc];
                        c1[j] = rp[HW_ * HW_ + gc];
                        c2[j] = rp[2 * HW_ * HW_ + gc];
                    }
                }
            }
        }
        const int ccb = 4 * vec - 1;               // tile col of elem 0
        u32_t* up = uniS + (row * 37 + ccb) * 2;
        #pragma unroll
        for (int j = 0; j < 4; ++j) {
            if ((unsigned)(ccb + j) < 37u) {
                u32x2 w;
                w[0] = packbf(c0[j], c1[j]);
                w[1] = packbf(c2[j], 1.0f);        // ch3 = 1.0 carries BN shift
                *(u32x2_ma*)(up + 2 * j) = w;
            }
        }
    }

    // ---- conv1 B-frags + ptab offsets from tables (pre-barrier) ----
    u32x4 wf[3];
    const u32x4_ma* wft = (const u32x4_ma*)(tab + WF_OFF);
    #pragma unroll
    for (int s = 0; s < 3; ++s) wf[s] = wft[s * 64 + lane];
    u32_t pofs[5];
    #pragma unroll
    for (int i = 0; i < 5; ++i) pofs[i] = tab[PT_OFF + (wave + 8 * i) * 64 + lane];
    __syncthreads();

    // ---- Phase 1: conv1 via 32x32x16 MFMA (3 K-steps), pool in-reg -> hS ----
    // MFMA output already includes BN scale+shift (folded into wf).
    const int hsub = n32 & 7;                      // within-chunk ch offset
    const int hchk = n32 >> 3;                     // logical ch-chunk
    const int pbase = wave * 8 + halfk;            // pD = pbase + i*64 + 2q

    // per-q hS store bases (u16 units); trip i adds immediate i*2048
    int hqi[4];
    #pragma unroll
    for (int q = 0; q < 4; ++q)
        hqi[q] = wave * 256 + halfk * 32 + hsub + q * 64 + ((hchk ^ q) << 3);

    const f32x16 z16 = {0.f,0.f,0.f,0.f,0.f,0.f,0.f,0.f,
                        0.f,0.f,0.f,0.f,0.f,0.f,0.f,0.f};

    auto conv_trip = [&](int ii) -> f32x16 {
        const u32_t* bp = uniS + pofs[ii];
        u32x2 l0a = *(const u32x2_ma*)(bp);
        u32x2 l0b = *(const u32x2_ma*)(bp + 2);
        u32x2 l1a = *(const u32x2_ma*)(bp + 74);
        u32x2 l1b = *(const u32x2_ma*)(bp + 76);
        u32x2 l2a = *(const u32x2_ma*)(bp + 148);
        u32x2 l2b = *(const u32x2_ma*)(bp + 150);
        u32x4 a0; a0[0] = l0a[0]; a0[1] = l0a[1]; a0[2] = l0b[0]; a0[3] = l0b[1];
        u32x4 a1; a1[0] = l1a[0]; a1[1] = l1a[1]; a1[2] = l1b[0]; a1[3] = l1b[1];
        u32x4 a2; a2[0] = l2a[0]; a2[1] = l2a[1]; a2[2] = l2b[0]; a2[3] = l2b[1];
        f32x16 acc = __builtin_amdgcn_mfma_f32_32x32x16_bf16(asbf(a0), asbf(wf[0]), z16, 0, 0, 0);
        acc = __builtin_amdgcn_mfma_f32_32x32x16_bf16(asbf(a1), asbf(wf[1]), acc, 0, 0, 0);
        acc = __builtin_amdgcn_mfma_f32_32x32x16_bf16(asbf(a2), asbf(wf[2]), acc, 0, 0, 0);
        return acc;
    };

    // pool+ReLU: max3(a,b,c) then max3(r,d,0) -> 2 VALU + cvt (BN pre-folded)
    auto pool_val = [&](int ii, int q, const f32x16& acc) -> float {
        float val = fmaxf(fmaxf(fmaxf(fmaxf(acc[4 * q], acc[4 * q + 1]),
                                      acc[4 * q + 2]), acc[4 * q + 3]), 0.f);
        if (!interior) {              // edge tiles: zero outside global 64x64
            int pD  = pbase + ii * 64 + 2 * q;
            int gyD = (pD * 241) >> 12;
            int gxD = pD - gyD * 17;
            int y2 = 4 * fy0 - 1 + gyD, x2 = 4 * fx0 - 1 + gxD;
            if (y2 < 0 || y2 > 63 || x2 < 0 || x2 > 63) val = 0.f;
        }
        return val;
    };

    // trips 0..3: tt = wave+8i <= 31 -> all pD <= 255 < 289: plain stores
    #pragma unroll
    for (int i = 0; i < 4; ++i) {
        f32x16 acc = conv_trip(i);
        #pragma unroll
        for (int q = 0; q < 4; ++q)
            hS[hqi[q] + i * 2048] = f2bf(pool_val(i, q, acc));
    }
    // trip 4: waves 0..3 full (tt=32..35, pD<=287); wave 4 only q=0,halfk=0
    // (tt=36 -> pD=288); waves 5..7 write nothing -> skip entirely.
    if (wave < 4) {
        f32x16 acc = conv_trip(4);
        #pragma unroll
        for (int q = 0; q < 4; ++q)
            hS[hqi[q] + 4 * 2048] = f2bf(pool_val(4, q, acc));
    } else if (wave == 4) {
        f32x16 acc = conv_trip(4);
        float val = pool_val(4, 0, acc);
        if (halfk == 0) hS[hqi[0] + 4 * 2048] = f2bf(val);
    }
    __syncthreads();   // hS complete

    // ---- Phase 2: conv2, both oc-halves in one pass (shared ah frags) ----
    float* outp = out + (size_t)img * 16384;
    const f32x4 zero4 = {0.f, 0.f, 0.f, 0.f};
    const int mt  = wave & 1;                      // oc-tile within half
    const int nt0 = wave >> 1;                     // feat row 0..3
    const int cy2 = 2 * nt0 + ((r >> 1) & 1);      // A-side conv-out row
    const int cx2 = 2 * (r >> 2) + (r & 1);        // A-side conv-out col
    const int fy  = fy0 + nt0;
    const int p0  = 34 * cy2 + 2 * cx2;            // tap(0,0) h-position

    const int oc0 = mt * 16 + r;
    const u32_t* wz0 = tab + W2R_OFF + oc0 * 16 + quad * 4;
    const u32_t* wz1 = wz0 + 4608;
    const float s2_0  = __uint_as_float(tab[BN2_OFF + 2 * oc0]);
    const float sh2_0 = __uint_as_float(tab[BN2_OFF + 2 * oc0 + 1]);
    const float s2_1  = __uint_as_float(tab[BN2_OFF + 64 + 2 * oc0]);
    const float sh2_1 = __uint_as_float(tab[BN2_OFF + 64 + 2 * oc0 + 1]);

    auto ld_ah = [&](int p) -> bf16x8 {
        return ld_frag16(&hS[p * 32 + (((quad ^ (p >> 1)) & 3) << 3)]);
    };

    f32x4 acc0 = zero4, acc1 = zero4;
    bf16x8 w0a = ld_frag32(wz0);
    bf16x8 w1a = ld_frag32(wz1);
    bf16x8 w0b = ld_frag32(wz0 + 512);
    bf16x8 w1b = ld_frag32(wz1 + 512);
    bf16x8 ahn = ld_ah(p0);
    #pragma unroll
    for (int s = 0; s < 9; ++s) {
        bf16x8 ah = ahn;
        if (s < 8) {
            const int ns = s + 1;
            const int nky = ns / 3, nkx = ns - 3 * nky;
            ahn = ld_ah(p0 + nky * 17 + nkx);
        }
        bf16x8 cw0 = w0a, cw1 = w1a;
        w0a = w0b; w1a = w1b;
        if (s < 7) {
            w0b = ld_frag32(wz0 + (s + 2) * 512);
            w1b = ld_frag32(wz1 + (s + 2) * 512);
        }
        acc0 = __builtin_amdgcn_mfma_f32_16x16x32_bf16(ah, cw0, acc0, 0, 0, 0);
        acc1 = __builtin_amdgcn_mfma_f32_16x16x32_bf16(ah, cw1, acc1, 0, 0, 0);
    }

    float m40 = fmaxf(fmaxf(fmaxf(acc0[0], acc0[1]), acc0[2]), acc0[3]);
    float z0  = fmaf(m40, s2_0, sh2_0);
    float sig0 = 1.f / (1.f + __expf(-z0));
    outp[oc0 * 256 + fy * 16 + fx0 + quad] = sig0;
    float m41 = fmaxf(fmaxf(fmaxf(acc1[0], acc1[1]), acc1[2]), acc1[3]);
    float z1  = fmaf(m41, s2_1, sh2_1);
    float sig1 = 1.f / (1.f + __expf(-z1));
    outp[(32 + oc0) * 256 + fy * 16 + fx0 + quad] = sig1;
    float ssum = sig0 + sig1;

    // ---- block score partial -> global atomic ----
    #pragma unroll
    for (int off = 32; off > 0; off >>= 1)
        ssum += __shfl_xor(ssum, off);
    if (lane == 0) redS[wave] = ssum;
    __syncthreads();
    if (tid == 0) {
        float bs = 0.f;
        #pragma unroll
        for (int w = 0; w < 8; ++w) bs += redS[w];
        atomicAdd(&wsum[img], bs);
    }
}

__global__ void finalize_kernel(const float* __restrict__ ws,
                                float* __restrict__ scores,
                                float* __restrict__ detected) {
    int i = threadIdx.x;
    float mean = ws[i] * (1.f / 16384.f);
    scores[i] = mean;
    detected[i] = (mean >= 0.55f) ? 1.f : 0.f;
}

extern "C" void kernel_launch(void* const* d_in, const int* in_sizes, int n_in,
                              void* d_out, int out_size, void* d_ws, size_t ws_size,
                              hipStream_t stream) {
    (void)in_sizes; (void)n_in; (void)out_size; (void)ws_size;
    const float* crops = (const float*)d_in[0];
    const float* w1  = (const float*)d_in[1];
    const float* b1  = (const float*)d_in[2];
    const float* g1  = (const float*)d_in[3];
    const float* be1 = (const float*)d_in[4];
    const float* m1  = (const float*)d_in[5];
    const float* v1  = (const float*)d_in[6];
    const float* w2  = (const float*)d_in[7];
    const float* b2  = (const float*)d_in[8];
    const float* g2  = (const float*)d_in[9];
    const float* be2 = (const float*)d_in[10];
    const float* m2  = (const float*)d_in[11];
    const float* v2  = (const float*)d_in[12];
    float* out = (float*)d_out;
    u32_t* ws  = (u32_t*)d_ws;

    prep_kernel<<<16, 512, 0, stream>>>(
        w1, b1, g1, be1, m1, v1, w2, b2, g2, be2, m2, v2, ws);
    fused_cnn_kernel<<<8192, 512, 0, stream>>>(
        crops, ws, out, (float*)ws);
    finalize_kernel<<<1, 512, 0, stream>>>(
        (const float*)ws, out + 8388608, out + 8388608 + 512);
}